// Round 1
// baseline (442.764 us; speedup 1.0000x reference)
//
#include <hip/hip_runtime.h>
#include <math.h>

// ---------------------------------------------------------------------------
// Problem constants
// ---------------------------------------------------------------------------
constexpr int B = 8;
constexpr int N = 2048;
constexpr int KNN = 20;
constexpr int H = 128;

// ws layout (float offsets)
constexpr int OWNPOS = 0;        // 64x3 normalized W_pos (192, pad 256)
constexpr int OWN1   = 256;      // 128x64  (8192)
constexpr int OWN2   = 8448;     // 128x256 (32768)
constexpr int OWN3   = 41216;    // 128x256 (32768)
constexpr int OPS1   = 73984;    // poolsum1 8*128*3 (3072)
constexpr int OPS2   = 77056;    // poolsum2 (3072)
constexpr int OPADD2 = 80128;    // (3072)
constexpr int ODADD2 = 83200;    // (3072)
constexpr int OPADD3 = 86272;    // (3072)
constexpr int ODADD3 = 89344;    // (3072)
constexpr int OIDX   = 92416;    // int region: 8*2048*20 = 327680 ints
constexpr int ONET0  = 420096;   // region A: net0 (then reused for net2), 6291456 floats
constexpr int ONET1  = 6711552;  // region B: net1, 6291456 floats
// total 13003008 floats = ~52 MB

// ---------------------------------------------------------------------------
// Wave-wide bitonic sort of 64 (value,index) pairs, descending by value,
// ties -> smaller index first (matches jax.lax.top_k tie-break).
// ---------------------------------------------------------------------------
__device__ __forceinline__ void wave_sort64(float& v, int& m, int lane) {
#pragma unroll
  for (int k = 2; k <= 64; k <<= 1) {
#pragma unroll
    for (int j = k >> 1; j > 0; j >>= 1) {
      float pv = __shfl_xor(v, j);
      int   pm = __shfl_xor(m, j);
      bool iam_lower   = (lane & j) == 0;
      bool dir_desc    = (lane & k) == 0;
      bool p_better    = (pv > v) || (pv == v && pm < m);
      bool want_better = (dir_desc == iam_lower);
      bool take        = (p_better == want_better);
      v = take ? pv : v;
      m = take ? pm : m;
    }
  }
}

// ---------------------------------------------------------------------------
// K1: normalize W rows (rows sum to 1).  448 rows total, one wave per row.
// ---------------------------------------------------------------------------
__global__ __launch_bounds__(256) void norm_rows_kernel(
    const float* __restrict__ Wpos, const float* __restrict__ W1,
    const float* __restrict__ W2, const float* __restrict__ W3,
    float* __restrict__ ws) {
  int r = blockIdx.x * 4 + (threadIdx.x >> 6);
  int lane = threadIdx.x & 63;
  const float* src;
  float* dst;
  int C;
  if (r < 64)       { src = Wpos + r * 3;          dst = ws + OWNPOS + r * 3;          C = 3;   }
  else if (r < 192) { int rr = r - 64;  src = W1 + rr * 64;  dst = ws + OWN1 + rr * 64;  C = 64;  }
  else if (r < 320) { int rr = r - 192; src = W2 + rr * 256; dst = ws + OWN2 + rr * 256; C = 256; }
  else              { int rr = r - 320; src = W3 + rr * 256; dst = ws + OWN3 + rr * 256; C = 256; }
  float s = 0.f;
  for (int i = lane; i < C; i += 64) s += src[i];
#pragma unroll
  for (int off = 32; off > 0; off >>= 1) s += __shfl_xor(s, off);
  for (int i = lane; i < C; i += 64) dst[i] = src[i] / s;
}

// ---------------------------------------------------------------------------
// K2: exact top-20 KNN by max of (2*inner - xx_q - xx_m).
// One wave per query; 32 candidates per lane in registers.
// Distances computed with _rn ops in jax evaluation order (bitwise stable
// so fp32 ties at the rank-20 boundary resolve exactly like lax.top_k).
// ---------------------------------------------------------------------------
__global__ __launch_bounds__(256) void knn_kernel(const float* __restrict__ pc,
                                                  int* __restrict__ idxout) {
  __shared__ float spx[N], spy[N], spz[N], sxx[N];
  __shared__ unsigned short sbuf[4][N];
  int tid = threadIdx.x;
  int b = blockIdx.y;
  const float* pcb = pc + b * N * 3;
  for (int i = tid; i < N; i += 256) {
    float x = pcb[i * 3 + 0], y = pcb[i * 3 + 1], z = pcb[i * 3 + 2];
    spx[i] = x; spy[i] = y; spz[i] = z;
    sxx[i] = __fadd_rn(__fadd_rn(__fmul_rn(x, x), __fmul_rn(y, y)), __fmul_rn(z, z));
  }
  __syncthreads();
  int wv = tid >> 6, lane = tid & 63;
  int q = blockIdx.x * 4 + wv;
  float qx = spx[q], qy = spy[q], qz = spz[q], qxx = sxx[q];

  float dv[32];
  float lmax = -INFINITY;
  int lm = 0;
#pragma unroll
  for (int i = 0; i < 32; ++i) {
    int m = i * 64 + lane;
    float inner = __fadd_rn(__fadd_rn(__fmul_rn(qx, spx[m]), __fmul_rn(qy, spy[m])),
                            __fmul_rn(qz, spz[m]));
    float d = __fsub_rn(__fsub_rn(__fmul_rn(2.0f, inner), qxx), sxx[m]);
    dv[i] = d;
    if (d > lmax) { lmax = d; lm = m; }
  }
  // threshold t = 20th-largest lane-max  (provably <= 20th-largest value)
  float sv = lmax; int sm = lm;
  wave_sort64(sv, sm, lane);
  float tval = __shfl(sv, 19);

  // compact survivors (d >= t); guaranteed >= 20 of them
  int base = 0;
#pragma unroll
  for (int i = 0; i < 32; ++i) {
    bool s = dv[i] >= tval;
    unsigned long long mk = __ballot(s);
    if (s) sbuf[wv][base + (int)__popcll(mk & ((1ull << lane) - 1ull))] =
        (unsigned short)(i * 64 + lane);
    base += (int)__popcll(mk);
  }
  int S = base;

  // merge survivors 44-at-a-time: lanes 0..19 hold running top-20
  float cv = -INFINITY;
  int cm = 0x7fffffff;
  int pos = 0;
  while (pos < S) {
    if (lane >= 20) {
      int t = pos + lane - 20;
      if (t < S) {
        int m = sbuf[wv][t];
        float inner = __fadd_rn(__fadd_rn(__fmul_rn(qx, spx[m]), __fmul_rn(qy, spy[m])),
                                __fmul_rn(qz, spz[m]));
        cv = __fsub_rn(__fsub_rn(__fmul_rn(2.0f, inner), qxx), sxx[m]);
        cm = m;
      } else {
        cv = -INFINITY; cm = 0x7fffffff;
      }
    }
    wave_sort64(cv, cm, lane);
    pos += 44;
  }
  if (lane < 20) idxout[(b * N + q) * KNN + lane] = cm;
}

// ---------------------------------------------------------------------------
// K3: edge features (nbr-ctr, ctr, cross(nbr,ctr)) -> pos layer (64ch) ->
// VN-LeakyReLU -> mean over k.   net0[b][o<64][vec][n]
// One thread per n, 4 output channels per thread.
// ---------------------------------------------------------------------------
__global__ __launch_bounds__(256) void edge_pos_kernel(
    const float* __restrict__ pc, const int* __restrict__ knn,
    const float* __restrict__ Wn, const float* __restrict__ Dp,
    float* __restrict__ net0) {
  int tid = threadIdx.x;
  int og = blockIdx.x, nt = blockIdx.y, b = blockIdx.z;
  int n = nt * 256 + tid;
  const float* pcb = pc + b * N * 3;
  float cx = pcb[n * 3 + 0], cy = pcb[n * 3 + 1], cz = pcb[n * 3 + 2];

  float w[4][3], dw[4][3], ax[4], ay[4], az[4];
#pragma unroll
  for (int j = 0; j < 4; ++j) {
    int o = og * 4 + j;
    w[j][0] = Wn[o * 3 + 0]; w[j][1] = Wn[o * 3 + 1]; w[j][2] = Wn[o * 3 + 2];
    dw[j][0] = Dp[o * 3 + 0]; dw[j][1] = Dp[o * 3 + 1]; dw[j][2] = Dp[o * 3 + 2];
    ax[j] = 0.f; ay[j] = 0.f; az[j] = 0.f;
  }
  const int* kn = knn + (b * N + n) * KNN;
  for (int k = 0; k < KNN; ++k) {
    int m = kn[k];
    float nx = pcb[m * 3 + 0], ny = pcb[m * 3 + 1], nz = pcb[m * 3 + 2];
    float ex = nx - cx, ey = ny - cy, ez = nz - cz;
    float rx = ny * cz - nz * cy;
    float ry = nz * cx - nx * cz;
    float rz = nx * cy - ny * cx;
#pragma unroll
    for (int j = 0; j < 4; ++j) {
      float px = fmaf(w[j][0], ex, fmaf(w[j][1], cx, w[j][2] * rx));
      float py = fmaf(w[j][0], ey, fmaf(w[j][1], cy, w[j][2] * ry));
      float pz = fmaf(w[j][0], ez, fmaf(w[j][1], cz, w[j][2] * rz));
      float dx = fmaf(dw[j][0], ex, fmaf(dw[j][1], cx, dw[j][2] * rx));
      float dy = fmaf(dw[j][0], ey, fmaf(dw[j][1], cy, dw[j][2] * ry));
      float dz = fmaf(dw[j][0], ez, fmaf(dw[j][1], cz, dw[j][2] * rz));
      float dot = fmaf(px, dx, fmaf(py, dy, pz * dz));
      float dns = fmaf(dx, dx, fmaf(dy, dy, dz * dz));
      float f = (dot < 0.f) ? dot / (dns + 1e-6f) : 0.f;
      ax[j] += px - f * dx;
      ay[j] += py - f * dy;
      az[j] += pz - f * dz;
    }
  }
#pragma unroll
  for (int j = 0; j < 4; ++j) {
    int o = og * 4 + j;
    net0[((b * 64 + o) * 3 + 0) * N + n] = ax[j] * (1.f / 20.f);
    net0[((b * 64 + o) * 3 + 1) * N + n] = ay[j] * (1.f / 20.f);
    net0[((b * 64 + o) * 3 + 2) * N + n] = az[j] * (1.f / 20.f);
  }
}

// ---------------------------------------------------------------------------
// K4/K6/K8: VNT layer.  X[b][C][3][N] -> 128 out channels, VN-LeakyReLU.
// Optional pAdd/dAdd: precomputed pooled-concat contribution (per b,o,vec).
// Optional poolsum: atomic per-(b,o,vec) sum over N of the output.
// Optional outAcc: atomic accumulation of mean-over-N directly into d_out.
// 2048 blocks, XCD-swizzled so the 32 blocks sharing an X-tile co-locate.
// ---------------------------------------------------------------------------
__global__ __launch_bounds__(256) void vnt_layer_kernel(
    const float* __restrict__ X, const float* __restrict__ Wn,
    const float* __restrict__ Dm, int C, int ldw,
    const float* __restrict__ pAdd, const float* __restrict__ dAdd,
    float* __restrict__ Y, float* __restrict__ poolsum,
    float* __restrict__ outAcc) {
  int tid = threadIdx.x;
  int flat = blockIdx.x;
  int xcd = flat & 7;
  int s = flat >> 3;
  int og = s & 31;
  int gl = s >> 5;
  int b = gl, nt = xcd;
  int n = nt * 256 + tid;
  int o0 = og * 4;

  float ap[4][3], ad[4][3];
#pragma unroll
  for (int j = 0; j < 4; ++j)
#pragma unroll
    for (int v = 0; v < 3; ++v) {
      ap[j][v] = pAdd ? pAdd[(b * H + o0 + j) * 3 + v] : 0.f;
      ad[j][v] = dAdd ? dAdd[(b * H + o0 + j) * 3 + v] : 0.f;
    }

  for (int c = 0; c < C; ++c) {
    float x0 = X[((b * C + c) * 3 + 0) * N + n];
    float x1 = X[((b * C + c) * 3 + 1) * N + n];
    float x2 = X[((b * C + c) * 3 + 2) * N + n];
#pragma unroll
    for (int j = 0; j < 4; ++j) {
      float wv_ = Wn[(o0 + j) * ldw + c];
      float dv_ = Dm[(o0 + j) * ldw + c];
      ap[j][0] = fmaf(wv_, x0, ap[j][0]);
      ap[j][1] = fmaf(wv_, x1, ap[j][1]);
      ap[j][2] = fmaf(wv_, x2, ap[j][2]);
      ad[j][0] = fmaf(dv_, x0, ad[j][0]);
      ad[j][1] = fmaf(dv_, x1, ad[j][1]);
      ad[j][2] = fmaf(dv_, x2, ad[j][2]);
    }
  }

  float res[4][3];
#pragma unroll
  for (int j = 0; j < 4; ++j) {
    float p0 = ap[j][0], p1 = ap[j][1], p2 = ap[j][2];
    float d0 = ad[j][0], d1 = ad[j][1], d2 = ad[j][2];
    float dot = fmaf(p0, d0, fmaf(p1, d1, p2 * d2));
    float dns = fmaf(d0, d0, fmaf(d1, d1, d2 * d2));
    float f = (dot < 0.f) ? dot / (dns + 1e-6f) : 0.f;
    res[j][0] = p0 - f * d0;
    res[j][1] = p1 - f * d1;
    res[j][2] = p2 - f * d2;
  }

  if (Y) {
#pragma unroll
    for (int j = 0; j < 4; ++j)
#pragma unroll
      for (int v = 0; v < 3; ++v)
        Y[((b * H + o0 + j) * 3 + v) * N + n] = res[j][v];
  }

  if (poolsum || outAcc) {
    __shared__ float red[12][4];
#pragma unroll
    for (int jv = 0; jv < 12; ++jv) {
      float r = res[jv / 3][jv % 3];
#pragma unroll
      for (int off = 32; off > 0; off >>= 1) r += __shfl_down(r, off);
      if ((tid & 63) == 0) red[jv][tid >> 6] = r;
    }
    __syncthreads();
    if (tid < 12) {
      float t = red[tid][0] + red[tid][1] + red[tid][2] + red[tid][3];
      int j = tid / 3, v = tid % 3;
      if (poolsum)
        atomicAdd(poolsum + (b * H + o0 + j) * 3 + v, t);
      else
        atomicAdd(outAcc + b * 384 + (o0 + j) * 3 + v, t * (1.f / 2048.f));
    }
  }
}

// ---------------------------------------------------------------------------
// K5/K7: project pooled mean through second half of W/D for next layer.
// pAdd[b][o][v] = sum_c Wn[o][colOff+c] * (poolsum[b][c][v] / N)
// ---------------------------------------------------------------------------
__global__ __launch_bounds__(256) void pool_project_kernel(
    const float* __restrict__ poolsum, const float* __restrict__ Wn,
    const float* __restrict__ Dm, int ldw, int colOff,
    float* __restrict__ pAdd, float* __restrict__ dAdd) {
  int t = blockIdx.x * 256 + threadIdx.x;
  if (t >= B * H * 3) return;
  int v = t % 3;
  int o = (t / 3) % H;
  int b = t / (H * 3);
  float sp = 0.f, sd = 0.f;
  for (int c = 0; c < H; ++c) {
    float x = poolsum[(b * H + c) * 3 + v];
    sp = fmaf(Wn[o * ldw + colOff + c], x, sp);
    sd = fmaf(Dm[o * ldw + colOff + c], x, sd);
  }
  pAdd[t] = sp * (1.f / 2048.f);
  dAdd[t] = sd * (1.f / 2048.f);
}

// ---------------------------------------------------------------------------
// launch
// ---------------------------------------------------------------------------
extern "C" void kernel_launch(void* const* d_in, const int* in_sizes, int n_in,
                              void* d_out, int out_size, void* d_ws, size_t ws_size,
                              hipStream_t stream) {
  (void)in_sizes; (void)n_in; (void)out_size; (void)ws_size;
  const float* pc   = (const float*)d_in[0];
  const float* Wpos = (const float*)d_in[1];
  const float* Dpos = (const float*)d_in[2];
  const float* W1   = (const float*)d_in[3];
  const float* D1   = (const float*)d_in[4];
  const float* W2   = (const float*)d_in[5];
  const float* D2   = (const float*)d_in[6];
  const float* W3   = (const float*)d_in[7];
  const float* D3   = (const float*)d_in[8];
  float* out = (float*)d_out;
  float* ws  = (float*)d_ws;

  hipMemsetAsync(ws + OPS1, 0, 2 * 3072 * sizeof(float), stream);  // poolsum1+2
  hipMemsetAsync(out, 0, B * 384 * sizeof(float), stream);

  norm_rows_kernel<<<112, 256, 0, stream>>>(Wpos, W1, W2, W3, ws);
  knn_kernel<<<dim3(N / 4, B), 256, 0, stream>>>(pc, (int*)(ws + OIDX));
  edge_pos_kernel<<<dim3(16, 8, 8), 256, 0, stream>>>(
      pc, (const int*)(ws + OIDX), ws + OWNPOS, Dpos, ws + ONET0);
  // layer1: 64 -> 128, pool epilogue
  vnt_layer_kernel<<<2048, 256, 0, stream>>>(
      ws + ONET0, ws + OWN1, D1, 64, 64, nullptr, nullptr,
      ws + ONET1, ws + OPS1, nullptr);
  // project pooled(net1) through W2/D2 second half
  pool_project_kernel<<<12, 256, 0, stream>>>(
      ws + OPS1, ws + OWN2, D2, 256, 128, ws + OPADD2, ws + ODADD2);
  // layer2: 128(+pool) -> 128, pool epilogue; net2 reuses net0 region
  vnt_layer_kernel<<<2048, 256, 0, stream>>>(
      ws + ONET1, ws + OWN2, D2, 128, 256, ws + OPADD2, ws + ODADD2,
      ws + ONET0, ws + OPS2, nullptr);
  pool_project_kernel<<<12, 256, 0, stream>>>(
      ws + OPS2, ws + OWN3, D3, 256, 128, ws + OPADD3, ws + ODADD3);
  // layer3: 128(+pool) -> 128, mean over N atomically into d_out
  vnt_layer_kernel<<<2048, 256, 0, stream>>>(
      ws + ONET0, ws + OWN3, D3, 128, 256, ws + OPADD3, ws + ODADD3,
      nullptr, nullptr, out);
}

// Round 2
// 370.205 us; speedup vs baseline: 1.1960x; 1.1960x over previous
//
#include <hip/hip_runtime.h>
#include <math.h>

// ---------------------------------------------------------------------------
// Problem constants
// ---------------------------------------------------------------------------
constexpr int B = 8;
constexpr int N = 2048;
constexpr int KNN = 20;
constexpr int H = 128;

// ws layout (float offsets)
constexpr int OWNPOS = 0;        // 64x3 normalized W_pos (192, pad 256)
constexpr int OWN1   = 256;      // 128x64  (8192)
constexpr int OWN2   = 8448;     // 128x256 (32768)
constexpr int OWN3   = 41216;    // 128x256 (32768)
constexpr int OPS1   = 73984;    // poolsum1 8*128*3 (3072)
constexpr int OPS2   = 77056;    // poolsum2 (3072)
constexpr int OPADD2 = 80128;    // (3072)
constexpr int ODADD2 = 83200;    // (3072)
constexpr int OPADD3 = 86272;    // (3072)
constexpr int ODADD3 = 89344;    // (3072)
constexpr int OIDX   = 92416;    // int region: 8*2048*20 = 327680 ints
constexpr int ONET0  = 420096;   // region A: net0 (then reused for net2), 6291456 floats
constexpr int ONET1  = 6711552;  // region B: net1, 6291456 floats
// total 13003008 floats = ~52 MB

// ---------------------------------------------------------------------------
// Wave-wide bitonic sort of 64 (value,index) pairs, descending by value,
// ties -> smaller index first (matches jax.lax.top_k tie-break).
// ---------------------------------------------------------------------------
__device__ __forceinline__ void wave_sort64(float& v, int& m, int lane) {
#pragma unroll
  for (int k = 2; k <= 64; k <<= 1) {
#pragma unroll
    for (int j = k >> 1; j > 0; j >>= 1) {
      float pv = __shfl_xor(v, j);
      int   pm = __shfl_xor(m, j);
      bool iam_lower   = (lane & j) == 0;
      bool dir_desc    = (lane & k) == 0;
      bool p_better    = (pv > v) || (pv == v && pm < m);
      bool want_better = (dir_desc == iam_lower);
      bool take        = (p_better == want_better);
      v = take ? pv : v;
      m = take ? pm : m;
    }
  }
}

// ---------------------------------------------------------------------------
// K1: normalize W rows (rows sum to 1).  448 rows total, one wave per row.
// ---------------------------------------------------------------------------
__global__ __launch_bounds__(256) void norm_rows_kernel(
    const float* __restrict__ Wpos, const float* __restrict__ W1,
    const float* __restrict__ W2, const float* __restrict__ W3,
    float* __restrict__ ws) {
  int r = blockIdx.x * 4 + (threadIdx.x >> 6);
  int lane = threadIdx.x & 63;
  const float* src;
  float* dst;
  int C;
  if (r < 64)       { src = Wpos + r * 3;          dst = ws + OWNPOS + r * 3;          C = 3;   }
  else if (r < 192) { int rr = r - 64;  src = W1 + rr * 64;  dst = ws + OWN1 + rr * 64;  C = 64;  }
  else if (r < 320) { int rr = r - 192; src = W2 + rr * 256; dst = ws + OWN2 + rr * 256; C = 256; }
  else              { int rr = r - 320; src = W3 + rr * 256; dst = ws + OWN3 + rr * 256; C = 256; }
  float s = 0.f;
  for (int i = lane; i < C; i += 64) s += src[i];
#pragma unroll
  for (int off = 32; off > 0; off >>= 1) s += __shfl_xor(s, off);
  for (int i = lane; i < C; i += 64) dst[i] = src[i] / s;
}

// ---------------------------------------------------------------------------
// K2: exact top-20 KNN by max of (2*inner - xx_q - xx_m).
// One wave per query; 32 candidates per lane in registers.
// ---------------------------------------------------------------------------
__global__ __launch_bounds__(256) void knn_kernel(const float* __restrict__ pc,
                                                  int* __restrict__ idxout) {
  __shared__ float spx[N], spy[N], spz[N], sxx[N];
  __shared__ unsigned short sbuf[4][N];
  int tid = threadIdx.x;
  int b = blockIdx.y;
  const float* pcb = pc + b * N * 3;
  for (int i = tid; i < N; i += 256) {
    float x = pcb[i * 3 + 0], y = pcb[i * 3 + 1], z = pcb[i * 3 + 2];
    spx[i] = x; spy[i] = y; spz[i] = z;
    sxx[i] = __fadd_rn(__fadd_rn(__fmul_rn(x, x), __fmul_rn(y, y)), __fmul_rn(z, z));
  }
  __syncthreads();
  int wv = tid >> 6, lane = tid & 63;
  int q = blockIdx.x * 4 + wv;
  float qx = spx[q], qy = spy[q], qz = spz[q], qxx = sxx[q];

  float dv[32];
  float lmax = -INFINITY;
  int lm = 0;
#pragma unroll
  for (int i = 0; i < 32; ++i) {
    int m = i * 64 + lane;
    float inner = __fadd_rn(__fadd_rn(__fmul_rn(qx, spx[m]), __fmul_rn(qy, spy[m])),
                            __fmul_rn(qz, spz[m]));
    float d = __fsub_rn(__fsub_rn(__fmul_rn(2.0f, inner), qxx), sxx[m]);
    dv[i] = d;
    if (d > lmax) { lmax = d; lm = m; }
  }
  // threshold t = 20th-largest lane-max  (provably <= 20th-largest value)
  float sv = lmax; int sm = lm;
  wave_sort64(sv, sm, lane);
  float tval = __shfl(sv, 19);

  // compact survivors (d >= t); guaranteed >= 20 of them
  int base = 0;
#pragma unroll
  for (int i = 0; i < 32; ++i) {
    bool s = dv[i] >= tval;
    unsigned long long mk = __ballot(s);
    if (s) sbuf[wv][base + (int)__popcll(mk & ((1ull << lane) - 1ull))] =
        (unsigned short)(i * 64 + lane);
    base += (int)__popcll(mk);
  }
  int S = base;

  // merge survivors 44-at-a-time: lanes 0..19 hold running top-20
  float cv = -INFINITY;
  int cm = 0x7fffffff;
  int pos = 0;
  while (pos < S) {
    if (lane >= 20) {
      int t = pos + lane - 20;
      if (t < S) {
        int m = sbuf[wv][t];
        float inner = __fadd_rn(__fadd_rn(__fmul_rn(qx, spx[m]), __fmul_rn(qy, spy[m])),
                                __fmul_rn(qz, spz[m]));
        cv = __fsub_rn(__fsub_rn(__fmul_rn(2.0f, inner), qxx), sxx[m]);
        cm = m;
      } else {
        cv = -INFINITY; cm = 0x7fffffff;
      }
    }
    wave_sort64(cv, cm, lane);
    pos += 44;
  }
  if (lane < 20) idxout[(b * N + q) * KNN + lane] = cm;
}

// ---------------------------------------------------------------------------
// K3: edge features (nbr-ctr, ctr, cross(nbr,ctr)) -> pos layer (64ch) ->
// VN-LeakyReLU -> mean over k.   net0[b][o<64][vec][n]
// ---------------------------------------------------------------------------
__global__ __launch_bounds__(256) void edge_pos_kernel(
    const float* __restrict__ pc, const int* __restrict__ knn,
    const float* __restrict__ Wn, const float* __restrict__ Dp,
    float* __restrict__ net0) {
  int tid = threadIdx.x;
  int og = blockIdx.x, nt = blockIdx.y, b = blockIdx.z;
  int n = nt * 256 + tid;
  const float* pcb = pc + b * N * 3;
  float cx = pcb[n * 3 + 0], cy = pcb[n * 3 + 1], cz = pcb[n * 3 + 2];

  float w[4][3], dw[4][3], ax[4], ay[4], az[4];
#pragma unroll
  for (int j = 0; j < 4; ++j) {
    int o = og * 4 + j;
    w[j][0] = Wn[o * 3 + 0]; w[j][1] = Wn[o * 3 + 1]; w[j][2] = Wn[o * 3 + 2];
    dw[j][0] = Dp[o * 3 + 0]; dw[j][1] = Dp[o * 3 + 1]; dw[j][2] = Dp[o * 3 + 2];
    ax[j] = 0.f; ay[j] = 0.f; az[j] = 0.f;
  }
  const int* kn = knn + (b * N + n) * KNN;
  for (int k = 0; k < KNN; ++k) {
    int m = kn[k];
    float nx = pcb[m * 3 + 0], ny = pcb[m * 3 + 1], nz = pcb[m * 3 + 2];
    float ex = nx - cx, ey = ny - cy, ez = nz - cz;
    float rx = ny * cz - nz * cy;
    float ry = nz * cx - nx * cz;
    float rz = nx * cy - ny * cx;
#pragma unroll
    for (int j = 0; j < 4; ++j) {
      float px = fmaf(w[j][0], ex, fmaf(w[j][1], cx, w[j][2] * rx));
      float py = fmaf(w[j][0], ey, fmaf(w[j][1], cy, w[j][2] * ry));
      float pz = fmaf(w[j][0], ez, fmaf(w[j][1], cz, w[j][2] * rz));
      float dx = fmaf(dw[j][0], ex, fmaf(dw[j][1], cx, dw[j][2] * rx));
      float dy = fmaf(dw[j][0], ey, fmaf(dw[j][1], cy, dw[j][2] * ry));
      float dz = fmaf(dw[j][0], ez, fmaf(dw[j][1], cz, dw[j][2] * rz));
      float dot = fmaf(px, dx, fmaf(py, dy, pz * dz));
      float dns = fmaf(dx, dx, fmaf(dy, dy, dz * dz));
      float f = (dot < 0.f) ? dot / (dns + 1e-6f) : 0.f;
      ax[j] += px - f * dx;
      ay[j] += py - f * dy;
      az[j] += pz - f * dz;
    }
  }
#pragma unroll
  for (int j = 0; j < 4; ++j) {
    int o = og * 4 + j;
    net0[((b * 64 + o) * 3 + 0) * N + n] = ax[j] * (1.f / 20.f);
    net0[((b * 64 + o) * 3 + 1) * N + n] = ay[j] * (1.f / 20.f);
    net0[((b * 64 + o) * 3 + 2) * N + n] = az[j] * (1.f / 20.f);
  }
}

// ---------------------------------------------------------------------------
// K4/K6/K8: VNT layer, ILP version.  X[b][C][3][N] -> 128 out, VN-LeakyReLU.
// 4 points per thread (float4 X loads), weights staged in LDS interleaved
// [c][j][w|d] so the inner loop reads them with 2 broadcast ds_read_b128.
// Grid 512: bid = og*16 + tile, tile = (b,nt).  With the typical bid%8
// XCD round-robin this co-locates all 32 og-blocks of one X-tile per XCD.
// ---------------------------------------------------------------------------
template <int C>
__global__ __launch_bounds__(256) void vnt_layer_kernel(
    const float* __restrict__ X, const float* __restrict__ Wn,
    const float* __restrict__ Dm, int ldw,
    const float* __restrict__ pAdd, const float* __restrict__ dAdd,
    float* __restrict__ Y, float* __restrict__ poolsum,
    float* __restrict__ outAcc) {
  __shared__ float wlds[C * 8];
  int tid = threadIdx.x;
  int bid = blockIdx.x;
  int tile = bid & 15;
  int og = bid >> 4;
  int b = tile >> 1, nt = tile & 1;
  int o0 = og * 4;

  for (int i = tid; i < C * 8; i += 256) {
    int c = i >> 3, sl = i & 7, j = sl >> 1;
    const float* src = (sl & 1) ? Dm : Wn;
    wlds[i] = src[(o0 + j) * ldw + c];
  }
  __syncthreads();

  int n0 = nt * 1024 + tid * 4;

  float ap[4][3][4], ad[4][3][4];
#pragma unroll
  for (int j = 0; j < 4; ++j)
#pragma unroll
    for (int v = 0; v < 3; ++v) {
      float pa = pAdd ? pAdd[(b * H + o0 + j) * 3 + v] : 0.f;
      float da = dAdd ? dAdd[(b * H + o0 + j) * 3 + v] : 0.f;
#pragma unroll
      for (int nn = 0; nn < 4; ++nn) { ap[j][v][nn] = pa; ad[j][v][nn] = da; }
    }

  const float* Xb = X + (size_t)b * C * 3 * N + n0;
#pragma unroll 2
  for (int c = 0; c < C; ++c) {
    float4 xv[3];
#pragma unroll
    for (int v = 0; v < 3; ++v)
      xv[v] = *(const float4*)(Xb + (c * 3 + v) * N);
    float4 wd0 = *(const float4*)(wlds + c * 8);
    float4 wd1 = *(const float4*)(wlds + c * 8 + 4);
    float wj[4] = {wd0.x, wd0.z, wd1.x, wd1.z};
    float dj[4] = {wd0.y, wd0.w, wd1.y, wd1.w};
#pragma unroll
    for (int j = 0; j < 4; ++j)
#pragma unroll
      for (int v = 0; v < 3; ++v) {
        const float* xp = (const float*)&xv[v];
#pragma unroll
        for (int nn = 0; nn < 4; ++nn) {
          ap[j][v][nn] = fmaf(wj[j], xp[nn], ap[j][v][nn]);
          ad[j][v][nn] = fmaf(dj[j], xp[nn], ad[j][v][nn]);
        }
      }
  }

  // VN-LeakyReLU in place (ap becomes the result)
#pragma unroll
  for (int j = 0; j < 4; ++j)
#pragma unroll
    for (int nn = 0; nn < 4; ++nn) {
      float p0 = ap[j][0][nn], p1 = ap[j][1][nn], p2 = ap[j][2][nn];
      float d0 = ad[j][0][nn], d1 = ad[j][1][nn], d2 = ad[j][2][nn];
      float dot = fmaf(p0, d0, fmaf(p1, d1, p2 * d2));
      float dns = fmaf(d0, d0, fmaf(d1, d1, d2 * d2));
      float f = (dot < 0.f) ? dot / (dns + 1e-6f) : 0.f;
      ap[j][0][nn] = p0 - f * d0;
      ap[j][1][nn] = p1 - f * d1;
      ap[j][2][nn] = p2 - f * d2;
    }

  if (Y) {
#pragma unroll
    for (int j = 0; j < 4; ++j)
#pragma unroll
      for (int v = 0; v < 3; ++v) {
        float4 r = make_float4(ap[j][v][0], ap[j][v][1], ap[j][v][2], ap[j][v][3]);
        *(float4*)(Y + ((size_t)(b * H + o0 + j) * 3 + v) * N + n0) = r;
      }
  }

  if (poolsum || outAcc) {
    __shared__ float red[12][4];
#pragma unroll
    for (int jv = 0; jv < 12; ++jv) {
      int j = jv / 3, v = jv % 3;
      float r = ap[j][v][0] + ap[j][v][1] + ap[j][v][2] + ap[j][v][3];
#pragma unroll
      for (int off = 32; off > 0; off >>= 1) r += __shfl_down(r, off);
      if ((tid & 63) == 0) red[jv][tid >> 6] = r;
    }
    __syncthreads();
    if (tid < 12) {
      float t = red[tid][0] + red[tid][1] + red[tid][2] + red[tid][3];
      int j = tid / 3, v = tid % 3;
      if (poolsum)
        atomicAdd(poolsum + (b * H + o0 + j) * 3 + v, t);
      else
        atomicAdd(outAcc + b * 384 + (o0 + j) * 3 + v, t * (1.f / 2048.f));
    }
  }
}

// ---------------------------------------------------------------------------
// K5/K7: project pooled mean through second half of W/D for next layer.
// ---------------------------------------------------------------------------
__global__ __launch_bounds__(256) void pool_project_kernel(
    const float* __restrict__ poolsum, const float* __restrict__ Wn,
    const float* __restrict__ Dm, int ldw, int colOff,
    float* __restrict__ pAdd, float* __restrict__ dAdd) {
  int t = blockIdx.x * 256 + threadIdx.x;
  if (t >= B * H * 3) return;
  int v = t % 3;
  int o = (t / 3) % H;
  int b = t / (H * 3);
  float sp = 0.f, sd = 0.f;
  for (int c = 0; c < H; ++c) {
    float x = poolsum[(b * H + c) * 3 + v];
    sp = fmaf(Wn[o * ldw + colOff + c], x, sp);
    sd = fmaf(Dm[o * ldw + colOff + c], x, sd);
  }
  pAdd[t] = sp * (1.f / 2048.f);
  dAdd[t] = sd * (1.f / 2048.f);
}

// ---------------------------------------------------------------------------
// launch
// ---------------------------------------------------------------------------
extern "C" void kernel_launch(void* const* d_in, const int* in_sizes, int n_in,
                              void* d_out, int out_size, void* d_ws, size_t ws_size,
                              hipStream_t stream) {
  (void)in_sizes; (void)n_in; (void)out_size; (void)ws_size;
  const float* pc   = (const float*)d_in[0];
  const float* Wpos = (const float*)d_in[1];
  const float* Dpos = (const float*)d_in[2];
  const float* W1   = (const float*)d_in[3];
  const float* D1   = (const float*)d_in[4];
  const float* W2   = (const float*)d_in[5];
  const float* D2   = (const float*)d_in[6];
  const float* W3   = (const float*)d_in[7];
  const float* D3   = (const float*)d_in[8];
  float* out = (float*)d_out;
  float* ws  = (float*)d_ws;

  hipMemsetAsync(ws + OPS1, 0, 2 * 3072 * sizeof(float), stream);  // poolsum1+2
  hipMemsetAsync(out, 0, B * 384 * sizeof(float), stream);

  norm_rows_kernel<<<112, 256, 0, stream>>>(Wpos, W1, W2, W3, ws);
  knn_kernel<<<dim3(N / 4, B), 256, 0, stream>>>(pc, (int*)(ws + OIDX));
  edge_pos_kernel<<<dim3(16, 8, 8), 256, 0, stream>>>(
      pc, (const int*)(ws + OIDX), ws + OWNPOS, Dpos, ws + ONET0);
  // layer1: 64 -> 128, pool epilogue
  vnt_layer_kernel<64><<<512, 256, 0, stream>>>(
      ws + ONET0, ws + OWN1, D1, 64, nullptr, nullptr,
      ws + ONET1, ws + OPS1, nullptr);
  // project pooled(net1) through W2/D2 second half
  pool_project_kernel<<<12, 256, 0, stream>>>(
      ws + OPS1, ws + OWN2, D2, 256, 128, ws + OPADD2, ws + ODADD2);
  // layer2: 128(+pool) -> 128, pool epilogue; net2 reuses net0 region
  vnt_layer_kernel<128><<<512, 256, 0, stream>>>(
      ws + ONET1, ws + OWN2, D2, 256, ws + OPADD2, ws + ODADD2,
      ws + ONET0, ws + OPS2, nullptr);
  pool_project_kernel<<<12, 256, 0, stream>>>(
      ws + OPS2, ws + OWN3, D3, 256, 128, ws + OPADD3, ws + ODADD3);
  // layer3: 128(+pool) -> 128, mean over N atomically into d_out
  vnt_layer_kernel<128><<<512, 256, 0, stream>>>(
      ws + ONET0, ws + OWN3, D3, 256, ws + OPADD3, ws + ODADD3,
      nullptr, nullptr, out);
}

// Round 3
// 326.445 us; speedup vs baseline: 1.3563x; 1.1341x over previous
//
#include <hip/hip_runtime.h>
#include <math.h>

// ---------------------------------------------------------------------------
// Problem constants
// ---------------------------------------------------------------------------
constexpr int B = 8;
constexpr int N = 2048;
constexpr int KNN = 20;
constexpr int H = 128;

// ws layout (float offsets)
constexpr int OWNPOS = 0;        // 64x3 normalized W_pos (192, pad 256)
constexpr int OWN1   = 256;      // 128x64  (8192)
constexpr int OWN2   = 8448;     // 128x256 (32768)
constexpr int OWN3   = 41216;    // 128x256 (32768)
constexpr int OPS1   = 73984;    // poolsum1 8*128*3 (3072)
constexpr int OPS2   = 77056;    // poolsum2 (3072)
constexpr int OIDX   = 92416;    // int region: 8*2048*20 = 327680 ints
constexpr int ONET0  = 420096;   // region A: net0 (then reused for net2)
constexpr int ONET1  = 6711552;  // region B: net1
// total ~13M floats = ~52 MB

// ---------------------------------------------------------------------------
// Wave-wide bitonic sort of 64 (value,index) pairs, descending by value,
// ties -> smaller index first (matches jax.lax.top_k tie-break).
// ---------------------------------------------------------------------------
__device__ __forceinline__ void wave_sort64(float& v, int& m, int lane) {
#pragma unroll
  for (int k = 2; k <= 64; k <<= 1) {
#pragma unroll
    for (int j = k >> 1; j > 0; j >>= 1) {
      float pv = __shfl_xor(v, j);
      int   pm = __shfl_xor(m, j);
      bool iam_lower   = (lane & j) == 0;
      bool dir_desc    = (lane & k) == 0;
      bool p_better    = (pv > v) || (pv == v && pm < m);
      bool want_better = (dir_desc == iam_lower);
      bool take        = (p_better == want_better);
      v = take ? pv : v;
      m = take ? pm : m;
    }
  }
}

// ---------------------------------------------------------------------------
// K1: normalize W rows (rows sum to 1).  448 rows total, one wave per row.
// ---------------------------------------------------------------------------
__global__ __launch_bounds__(256) void norm_rows_kernel(
    const float* __restrict__ Wpos, const float* __restrict__ W1,
    const float* __restrict__ W2, const float* __restrict__ W3,
    float* __restrict__ ws) {
  int r = blockIdx.x * 4 + (threadIdx.x >> 6);
  int lane = threadIdx.x & 63;
  const float* src;
  float* dst;
  int C;
  if (r < 64)       { src = Wpos + r * 3;          dst = ws + OWNPOS + r * 3;          C = 3;   }
  else if (r < 192) { int rr = r - 64;  src = W1 + rr * 64;  dst = ws + OWN1 + rr * 64;  C = 64;  }
  else if (r < 320) { int rr = r - 192; src = W2 + rr * 256; dst = ws + OWN2 + rr * 256; C = 256; }
  else              { int rr = r - 320; src = W3 + rr * 256; dst = ws + OWN3 + rr * 256; C = 256; }
  float s = 0.f;
  for (int i = lane; i < C; i += 64) s += src[i];
#pragma unroll
  for (int off = 32; off > 0; off >>= 1) s += __shfl_xor(s, off);
  for (int i = lane; i < C; i += 64) dst[i] = src[i] / s;
}

// ---------------------------------------------------------------------------
// K2: exact top-20 KNN by max of (2*inner - xx_q - xx_m).
// One wave per query; 32 candidates per lane in registers.
// ---------------------------------------------------------------------------
__global__ __launch_bounds__(256) void knn_kernel(const float* __restrict__ pc,
                                                  int* __restrict__ idxout) {
  __shared__ float spx[N], spy[N], spz[N], sxx[N];
  __shared__ unsigned short sbuf[4][N];
  int tid = threadIdx.x;
  int b = blockIdx.y;
  const float* pcb = pc + b * N * 3;
  for (int i = tid; i < N; i += 256) {
    float x = pcb[i * 3 + 0], y = pcb[i * 3 + 1], z = pcb[i * 3 + 2];
    spx[i] = x; spy[i] = y; spz[i] = z;
    sxx[i] = __fadd_rn(__fadd_rn(__fmul_rn(x, x), __fmul_rn(y, y)), __fmul_rn(z, z));
  }
  __syncthreads();
  int wv = tid >> 6, lane = tid & 63;
  int q = blockIdx.x * 4 + wv;
  float qx = spx[q], qy = spy[q], qz = spz[q], qxx = sxx[q];

  float dv[32];
  float lmax = -INFINITY;
  int lm = 0;
#pragma unroll
  for (int i = 0; i < 32; ++i) {
    int m = i * 64 + lane;
    float inner = __fadd_rn(__fadd_rn(__fmul_rn(qx, spx[m]), __fmul_rn(qy, spy[m])),
                            __fmul_rn(qz, spz[m]));
    float d = __fsub_rn(__fsub_rn(__fmul_rn(2.0f, inner), qxx), sxx[m]);
    dv[i] = d;
    if (d > lmax) { lmax = d; lm = m; }
  }
  // threshold t = 20th-largest lane-max  (provably <= 20th-largest value)
  float sv = lmax; int sm = lm;
  wave_sort64(sv, sm, lane);
  float tval = __shfl(sv, 19);

  // compact survivors (d >= t); guaranteed >= 20 of them
  int base = 0;
#pragma unroll
  for (int i = 0; i < 32; ++i) {
    bool s = dv[i] >= tval;
    unsigned long long mk = __ballot(s);
    if (s) sbuf[wv][base + (int)__popcll(mk & ((1ull << lane) - 1ull))] =
        (unsigned short)(i * 64 + lane);
    base += (int)__popcll(mk);
  }
  int S = base;

  // merge survivors 44-at-a-time: lanes 0..19 hold running top-20
  float cv = -INFINITY;
  int cm = 0x7fffffff;
  int pos = 0;
  while (pos < S) {
    if (lane >= 20) {
      int t = pos + lane - 20;
      if (t < S) {
        int m = sbuf[wv][t];
        float inner = __fadd_rn(__fadd_rn(__fmul_rn(qx, spx[m]), __fmul_rn(qy, spy[m])),
                                __fmul_rn(qz, spz[m]));
        cv = __fsub_rn(__fsub_rn(__fmul_rn(2.0f, inner), qxx), sxx[m]);
        cm = m;
      } else {
        cv = -INFINITY; cm = 0x7fffffff;
      }
    }
    wave_sort64(cv, cm, lane);
    pos += 44;
  }
  if (lane < 20) idxout[(b * N + q) * KNN + lane] = cm;
}

// ---------------------------------------------------------------------------
// K3: edge features (nbr-ctr, ctr, cross(nbr,ctr)) -> pos layer (64ch) ->
// VN-LeakyReLU -> mean over k.   net0[b][o<64][vec][n]
// ---------------------------------------------------------------------------
__global__ __launch_bounds__(256) void edge_pos_kernel(
    const float* __restrict__ pc, const int* __restrict__ knn,
    const float* __restrict__ Wn, const float* __restrict__ Dp,
    float* __restrict__ net0) {
  int tid = threadIdx.x;
  int og = blockIdx.x, nt = blockIdx.y, b = blockIdx.z;
  int n = nt * 256 + tid;
  const float* pcb = pc + b * N * 3;
  float cx = pcb[n * 3 + 0], cy = pcb[n * 3 + 1], cz = pcb[n * 3 + 2];

  float w[4][3], dw[4][3], ax[4], ay[4], az[4];
#pragma unroll
  for (int j = 0; j < 4; ++j) {
    int o = og * 4 + j;
    w[j][0] = Wn[o * 3 + 0]; w[j][1] = Wn[o * 3 + 1]; w[j][2] = Wn[o * 3 + 2];
    dw[j][0] = Dp[o * 3 + 0]; dw[j][1] = Dp[o * 3 + 1]; dw[j][2] = Dp[o * 3 + 2];
    ax[j] = 0.f; ay[j] = 0.f; az[j] = 0.f;
  }
  const int* kn = knn + (b * N + n) * KNN;
  for (int k = 0; k < KNN; ++k) {
    int m = kn[k];
    float nx = pcb[m * 3 + 0], ny = pcb[m * 3 + 1], nz = pcb[m * 3 + 2];
    float ex = nx - cx, ey = ny - cy, ez = nz - cz;
    float rx = ny * cz - nz * cy;
    float ry = nz * cx - nx * cz;
    float rz = nx * cy - ny * cx;
#pragma unroll
    for (int j = 0; j < 4; ++j) {
      float px = fmaf(w[j][0], ex, fmaf(w[j][1], cx, w[j][2] * rx));
      float py = fmaf(w[j][0], ey, fmaf(w[j][1], cy, w[j][2] * ry));
      float pz = fmaf(w[j][0], ez, fmaf(w[j][1], cz, w[j][2] * rz));
      float dx = fmaf(dw[j][0], ex, fmaf(dw[j][1], cx, dw[j][2] * rx));
      float dy = fmaf(dw[j][0], ey, fmaf(dw[j][1], cy, dw[j][2] * ry));
      float dz = fmaf(dw[j][0], ez, fmaf(dw[j][1], cz, dw[j][2] * rz));
      float dot = fmaf(px, dx, fmaf(py, dy, pz * dz));
      float dns = fmaf(dx, dx, fmaf(dy, dy, dz * dz));
      float f = (dot < 0.f) ? dot / (dns + 1e-6f) : 0.f;
      ax[j] += px - f * dx;
      ay[j] += py - f * dy;
      az[j] += pz - f * dz;
    }
  }
#pragma unroll
  for (int j = 0; j < 4; ++j) {
    int o = og * 4 + j;
    net0[((b * 64 + o) * 3 + 0) * N + n] = ax[j] * (1.f / 20.f);
    net0[((b * 64 + o) * 3 + 1) * N + n] = ay[j] * (1.f / 20.f);
    net0[((b * 64 + o) * 3 + 2) * N + n] = az[j] * (1.f / 20.f);
  }
}

// ---------------------------------------------------------------------------
// K4/K5/K6: VNT layer.  X[b][C][3][N] -> 128 out, VN-LeakyReLU.
// 2 points per thread (float2 X loads), 4 outputs per thread, weights staged
// in LDS interleaved [c][j][w|d].  1024 blocks -> 4 blocks/CU, 16 waves/CU.
// HASPOOL: the pooled-concat half (cols C..C+127 of W/D applied to
// poolsum/N) is computed in the prologue by this block (replaces the old
// pool_project kernel).
// bid = og*32 + (b*4+nt): all 32 og-blocks of one X-tile share bid%8 (XCD).
// ---------------------------------------------------------------------------
template <int C, bool HASPOOL>
__global__ __launch_bounds__(256, 4) void vnt_layer_kernel(
    const float* __restrict__ X, const float* __restrict__ Wn,
    const float* __restrict__ Dm, int ldw,
    const float* __restrict__ poolin,
    float* __restrict__ Y, float* __restrict__ poolsum,
    float* __restrict__ outAcc) {
  __shared__ float wlds[C * 8];
  __shared__ float partp[12][16], partd[12][16];
  __shared__ float spadd[12], sdadd[12];
  int tid = threadIdx.x;
  int bid = blockIdx.x;
  int og = bid >> 5;
  int tile = bid & 31;
  int b = tile >> 2, nt = tile & 3;
  int o0 = og * 4;

  for (int i = tid; i < C * 8; i += 256) {
    int c = i >> 3, sl = i & 7, j = sl >> 1;
    const float* src = (sl & 1) ? Dm : Wn;
    wlds[i] = src[(o0 + j) * ldw + c];
  }
  if (HASPOOL) {
    if (tid < 192) {
      int jv = tid >> 4, ch = tid & 15;
      int j = jv / 3, v = jv % 3;
      float sp = 0.f, sd = 0.f;
#pragma unroll
      for (int cc = 0; cc < 8; ++cc) {
        int c = ch * 8 + cc;
        float x = poolin[(b * H + c) * 3 + v];
        sp = fmaf(Wn[(o0 + j) * ldw + C + c], x, sp);
        sd = fmaf(Dm[(o0 + j) * ldw + C + c], x, sd);
      }
      partp[jv][ch] = sp;
      partd[jv][ch] = sd;
    }
    __syncthreads();
    if (tid < 24) {
      int jv = tid % 12;
      bool isd = tid >= 12;
      float s = 0.f;
#pragma unroll
      for (int ch = 0; ch < 16; ++ch) s += (isd ? partd : partp)[jv][ch];
      (isd ? sdadd : spadd)[jv] = s * (1.f / 2048.f);
    }
  }
  __syncthreads();

  int n0 = nt * 512 + tid * 2;

  float ap[4][3][2], ad[4][3][2];
#pragma unroll
  for (int j = 0; j < 4; ++j)
#pragma unroll
    for (int v = 0; v < 3; ++v) {
      float pa = HASPOOL ? spadd[j * 3 + v] : 0.f;
      float da = HASPOOL ? sdadd[j * 3 + v] : 0.f;
#pragma unroll
      for (int nn = 0; nn < 2; ++nn) { ap[j][v][nn] = pa; ad[j][v][nn] = da; }
    }

  const float* Xb = X + (size_t)b * C * 3 * N + n0;
#pragma unroll 2
  for (int c = 0; c < C; ++c) {
    float2 xv[3];
#pragma unroll
    for (int v = 0; v < 3; ++v)
      xv[v] = *(const float2*)(Xb + (c * 3 + v) * N);
    float4 wd0 = *(const float4*)(wlds + c * 8);
    float4 wd1 = *(const float4*)(wlds + c * 8 + 4);
    float wj[4] = {wd0.x, wd0.z, wd1.x, wd1.z};
    float dj[4] = {wd0.y, wd0.w, wd1.y, wd1.w};
#pragma unroll
    for (int j = 0; j < 4; ++j)
#pragma unroll
      for (int v = 0; v < 3; ++v) {
        const float* xp = (const float*)&xv[v];
#pragma unroll
        for (int nn = 0; nn < 2; ++nn) {
          ap[j][v][nn] = fmaf(wj[j], xp[nn], ap[j][v][nn]);
          ad[j][v][nn] = fmaf(dj[j], xp[nn], ad[j][v][nn]);
        }
      }
  }

  // VN-LeakyReLU in place (ap becomes the result)
#pragma unroll
  for (int j = 0; j < 4; ++j)
#pragma unroll
    for (int nn = 0; nn < 2; ++nn) {
      float p0 = ap[j][0][nn], p1 = ap[j][1][nn], p2 = ap[j][2][nn];
      float d0 = ad[j][0][nn], d1 = ad[j][1][nn], d2 = ad[j][2][nn];
      float dot = fmaf(p0, d0, fmaf(p1, d1, p2 * d2));
      float dns = fmaf(d0, d0, fmaf(d1, d1, d2 * d2));
      float f = (dot < 0.f) ? dot / (dns + 1e-6f) : 0.f;
      ap[j][0][nn] = p0 - f * d0;
      ap[j][1][nn] = p1 - f * d1;
      ap[j][2][nn] = p2 - f * d2;
    }

  if (Y) {
#pragma unroll
    for (int j = 0; j < 4; ++j)
#pragma unroll
      for (int v = 0; v < 3; ++v) {
        float2 r = make_float2(ap[j][v][0], ap[j][v][1]);
        *(float2*)(Y + ((size_t)(b * H + o0 + j) * 3 + v) * N + n0) = r;
      }
  }

  if (poolsum || outAcc) {
    __shared__ float red[12][4];
#pragma unroll
    for (int jv = 0; jv < 12; ++jv) {
      int j = jv / 3, v = jv % 3;
      float r = ap[j][v][0] + ap[j][v][1];
#pragma unroll
      for (int off = 32; off > 0; off >>= 1) r += __shfl_down(r, off);
      if ((tid & 63) == 0) red[jv][tid >> 6] = r;
    }
    __syncthreads();
    if (tid < 12) {
      float t = red[tid][0] + red[tid][1] + red[tid][2] + red[tid][3];
      int j = tid / 3, v = tid % 3;
      if (poolsum)
        atomicAdd(poolsum + (b * H + o0 + j) * 3 + v, t);
      else
        atomicAdd(outAcc + b * 384 + (o0 + j) * 3 + v, t * (1.f / 2048.f));
    }
  }
}

// ---------------------------------------------------------------------------
// launch
// ---------------------------------------------------------------------------
extern "C" void kernel_launch(void* const* d_in, const int* in_sizes, int n_in,
                              void* d_out, int out_size, void* d_ws, size_t ws_size,
                              hipStream_t stream) {
  (void)in_sizes; (void)n_in; (void)out_size; (void)ws_size;
  const float* pc   = (const float*)d_in[0];
  const float* Wpos = (const float*)d_in[1];
  const float* Dpos = (const float*)d_in[2];
  const float* W1   = (const float*)d_in[3];
  const float* D1   = (const float*)d_in[4];
  const float* W2   = (const float*)d_in[5];
  const float* D2   = (const float*)d_in[6];
  const float* W3   = (const float*)d_in[7];
  const float* D3   = (const float*)d_in[8];
  float* out = (float*)d_out;
  float* ws  = (float*)d_ws;

  hipMemsetAsync(ws + OPS1, 0, 2 * 3072 * sizeof(float), stream);  // poolsum1+2
  hipMemsetAsync(out, 0, B * 384 * sizeof(float), stream);

  norm_rows_kernel<<<112, 256, 0, stream>>>(Wpos, W1, W2, W3, ws);
  knn_kernel<<<dim3(N / 4, B), 256, 0, stream>>>(pc, (int*)(ws + OIDX));
  edge_pos_kernel<<<dim3(16, 8, 8), 256, 0, stream>>>(
      pc, (const int*)(ws + OIDX), ws + OWNPOS, Dpos, ws + ONET0);
  // layer1: 64 -> 128, pool epilogue
  vnt_layer_kernel<64, false><<<1024, 256, 0, stream>>>(
      ws + ONET0, ws + OWN1, D1, 64, nullptr,
      ws + ONET1, ws + OPS1, nullptr);
  // layer2: 128(+pool prologue) -> 128, pool epilogue; net2 reuses net0 region
  vnt_layer_kernel<128, true><<<1024, 256, 0, stream>>>(
      ws + ONET1, ws + OWN2, D2, 256, ws + OPS1,
      ws + ONET0, ws + OPS2, nullptr);
  // layer3: 128(+pool prologue) -> 128, mean over N atomically into d_out
  vnt_layer_kernel<128, true><<<1024, 256, 0, stream>>>(
      ws + ONET0, ws + OWN3, D3, 256, ws + OPS2,
      nullptr, nullptr, out);
}

// Round 4
// 316.142 us; speedup vs baseline: 1.4005x; 1.0326x over previous
//
#include <hip/hip_runtime.h>
#include <math.h>

// ---------------------------------------------------------------------------
// Problem constants
// ---------------------------------------------------------------------------
constexpr int B = 8;
constexpr int N = 2048;
constexpr int KNN = 20;
constexpr int H = 128;

// ws layout (float offsets)
constexpr int OWNPOS = 0;        // 64x3 normalized W_pos (192, pad 256)
constexpr int OWN1   = 256;      // 128x64  (8192)
constexpr int OWN2   = 8448;     // 128x256 (32768)
constexpr int OWN3   = 41216;    // 128x256 (32768)
constexpr int OPS1   = 73984;    // poolsum1 8*128*3 (3072)
constexpr int OPS2   = 77056;    // poolsum2 (3072)
constexpr int OIDX   = 92416;    // int region: 8*2048*20 = 327680 ints
constexpr int ONET0  = 420096;   // region A: net0 (then reused for net2)
constexpr int ONET1  = 6711552;  // region B: net1
// total ~13M floats = ~52 MB

// ---------------------------------------------------------------------------
// Wave-wide bitonic sort of 64 (value,index) pairs, descending by value,
// ties -> smaller index first (matches jax.lax.top_k tie-break).
// ---------------------------------------------------------------------------
__device__ __forceinline__ void wave_sort64(float& v, int& m, int lane) {
#pragma unroll
  for (int k = 2; k <= 64; k <<= 1) {
#pragma unroll
    for (int j = k >> 1; j > 0; j >>= 1) {
      float pv = __shfl_xor(v, j);
      int   pm = __shfl_xor(m, j);
      bool iam_lower   = (lane & j) == 0;
      bool dir_desc    = (lane & k) == 0;
      bool p_better    = (pv > v) || (pv == v && pm < m);
      bool want_better = (dir_desc == iam_lower);
      bool take        = (p_better == want_better);
      v = take ? pv : v;
      m = take ? pm : m;
    }
  }
}

// ---------------------------------------------------------------------------
// K1: normalize W rows (rows sum to 1).  448 rows total, one wave per row.
// ---------------------------------------------------------------------------
__global__ __launch_bounds__(256) void norm_rows_kernel(
    const float* __restrict__ Wpos, const float* __restrict__ W1,
    const float* __restrict__ W2, const float* __restrict__ W3,
    float* __restrict__ ws) {
  int r = blockIdx.x * 4 + (threadIdx.x >> 6);
  int lane = threadIdx.x & 63;
  const float* src;
  float* dst;
  int C;
  if (r < 64)       { src = Wpos + r * 3;          dst = ws + OWNPOS + r * 3;          C = 3;   }
  else if (r < 192) { int rr = r - 64;  src = W1 + rr * 64;  dst = ws + OWN1 + rr * 64;  C = 64;  }
  else if (r < 320) { int rr = r - 192; src = W2 + rr * 256; dst = ws + OWN2 + rr * 256; C = 256; }
  else              { int rr = r - 320; src = W3 + rr * 256; dst = ws + OWN3 + rr * 256; C = 256; }
  float s = 0.f;
  for (int i = lane; i < C; i += 64) s += src[i];
#pragma unroll
  for (int off = 32; off > 0; off >>= 1) s += __shfl_xor(s, off);
  for (int i = lane; i < C; i += 64) dst[i] = src[i] / s;
}

// ---------------------------------------------------------------------------
// K2: exact top-20 KNN by max of (2*inner - xx_q - xx_m).
// One wave per query.  Points staged in LDS as float4(2x,2y,2z,xx): the x2
// pre-scale is exact in fp32 (scaling by 2 commutes with round-to-nearest),
// so distances are bitwise identical to the jax evaluation order.
// Phase 1: 32 cands/lane, track lane-max (value only).
// Phase 2: radix-select the 20th-largest lane-max via 32 wave-uniform ballot
//          steps (no LDS pipe, no sort) -> threshold t <= 20th-largest value.
// Phase 3: ballot-compact survivors (d >= t, E[S]~24) and run ONE bitonic
//          sort64 (exact fallbacks for S>64 / S>512 kept for robustness).
// LDS 36KB -> 4 blocks/CU.
// ---------------------------------------------------------------------------
__global__ __launch_bounds__(256, 4) void knn_kernel(const float* __restrict__ pc,
                                                     int* __restrict__ idxout) {
  __shared__ float4 spt[N];                 // 32 KB
  __shared__ unsigned short sbuf[4][512];   // 4 KB
  int tid = threadIdx.x;
  int b = blockIdx.y;
  const float* pcb = pc + b * N * 3;
  for (int i = tid; i < N; i += 256) {
    float x = pcb[i * 3 + 0], y = pcb[i * 3 + 1], z = pcb[i * 3 + 2];
    float xx = __fadd_rn(__fadd_rn(__fmul_rn(x, x), __fmul_rn(y, y)), __fmul_rn(z, z));
    spt[i] = make_float4(2.f * x, 2.f * y, 2.f * z, xx);
  }
  __syncthreads();
  int wv = tid >> 6, lane = tid & 63;
  int q = blockIdx.x * 4 + wv;
  float4 qp = spt[q];
  float qx = 0.5f * qp.x, qy = 0.5f * qp.y, qz = 0.5f * qp.z, qxx = qp.w;

  // d(m) = ((2mx*qx + 2my*qy) + 2mz*qz - qxx) - mxx   (== jax bits)
  float dv[32];
  float lmax = -INFINITY;
#pragma unroll
  for (int i = 0; i < 32; ++i) {
    float4 m = spt[i * 64 + lane];
    float A = __fadd_rn(__fadd_rn(__fmul_rn(m.x, qx), __fmul_rn(m.y, qy)),
                        __fmul_rn(m.z, qz));
    float d = __fsub_rn(__fsub_rn(A, qxx), m.w);
    dv[i] = d;
    lmax = fmaxf(lmax, d);
  }

  // radix-select: ordered-uint of the 20th-largest lane-max (wave-uniform)
  unsigned u = __float_as_uint(lmax);
  u = u ^ ((u >> 31) ? 0xFFFFFFFFu : 0x80000000u);
  unsigned prefix = 0u;
#pragma unroll
  for (int bit = 31; bit >= 0; --bit) {
    unsigned test = prefix | (1u << bit);
    int cnt = (int)__popcll(__ballot(u >= test));
    if (cnt >= KNN) prefix = test;
  }
  float tval = __uint_as_float((prefix >> 31) ? (prefix ^ 0x80000000u) : ~prefix);

  // compact survivors (d >= tval); >= 20 guaranteed
  int base = 0;
#pragma unroll
  for (int i = 0; i < 32; ++i) {
    bool s = dv[i] >= tval;
    unsigned long long mk = __ballot(s);
    if (s) {
      int pos = base + (int)__popcll(mk & ((1ull << lane) - 1ull));
      if (pos < 512) sbuf[wv][pos] = (unsigned short)(i * 64 + lane);
    }
    base += (int)__popcll(mk);
  }
  int S = base;

  auto distOf = [&](int m) -> float {
    float4 mp = spt[m];
    float A = __fadd_rn(__fadd_rn(__fmul_rn(mp.x, qx), __fmul_rn(mp.y, qy)),
                        __fmul_rn(mp.z, qz));
    return __fsub_rn(__fsub_rn(A, qxx), mp.w);
  };

  float cv = -INFINITY;
  int cm = 0x7fffffff;
  if (S <= 64) {
    // the common path: one sort of all survivors
    if (lane < S) { cm = sbuf[wv][lane]; cv = distOf(cm); }
    wave_sort64(cv, cm, lane);
  } else if (S <= 512) {
    int pos = 0;
    while (pos < S) {
      if (lane >= KNN) {
        int t = pos + lane - KNN;
        if (t < S) { cm = sbuf[wv][t]; cv = distOf(cm); }
        else       { cm = 0x7fffffff;  cv = -INFINITY; }
      }
      wave_sort64(cv, cm, lane);
      pos += 64 - KNN;
    }
  } else {
    // exact full-scan fallback (never expected on this data)
    int pos = 0;
    while (pos < N) {
      if (lane >= KNN) {
        int t = pos + lane - KNN;
        if (t < N) { cm = t; cv = distOf(t); }
        else       { cm = 0x7fffffff; cv = -INFINITY; }
      }
      wave_sort64(cv, cm, lane);
      pos += 64 - KNN;
    }
  }
  if (lane < KNN) idxout[(b * N + q) * KNN + lane] = cm;
}

// ---------------------------------------------------------------------------
// K3: edge features (nbr-ctr, ctr, cross(nbr,ctr)) -> pos layer (64ch) ->
// VN-LeakyReLU -> mean over k.   net0[b][o<64][vec][n]
// ---------------------------------------------------------------------------
__global__ __launch_bounds__(256) void edge_pos_kernel(
    const float* __restrict__ pc, const int* __restrict__ knn,
    const float* __restrict__ Wn, const float* __restrict__ Dp,
    float* __restrict__ net0) {
  int tid = threadIdx.x;
  int og = blockIdx.x, nt = blockIdx.y, b = blockIdx.z;
  int n = nt * 256 + tid;
  const float* pcb = pc + b * N * 3;
  float cx = pcb[n * 3 + 0], cy = pcb[n * 3 + 1], cz = pcb[n * 3 + 2];

  float w[4][3], dw[4][3], ax[4], ay[4], az[4];
#pragma unroll
  for (int j = 0; j < 4; ++j) {
    int o = og * 4 + j;
    w[j][0] = Wn[o * 3 + 0]; w[j][1] = Wn[o * 3 + 1]; w[j][2] = Wn[o * 3 + 2];
    dw[j][0] = Dp[o * 3 + 0]; dw[j][1] = Dp[o * 3 + 1]; dw[j][2] = Dp[o * 3 + 2];
    ax[j] = 0.f; ay[j] = 0.f; az[j] = 0.f;
  }
  const int* kn = knn + (b * N + n) * KNN;
  for (int k = 0; k < KNN; ++k) {
    int m = kn[k];
    float nx = pcb[m * 3 + 0], ny = pcb[m * 3 + 1], nz = pcb[m * 3 + 2];
    float ex = nx - cx, ey = ny - cy, ez = nz - cz;
    float rx = ny * cz - nz * cy;
    float ry = nz * cx - nx * cz;
    float rz = nx * cy - ny * cx;
#pragma unroll
    for (int j = 0; j < 4; ++j) {
      float px = fmaf(w[j][0], ex, fmaf(w[j][1], cx, w[j][2] * rx));
      float py = fmaf(w[j][0], ey, fmaf(w[j][1], cy, w[j][2] * ry));
      float pz = fmaf(w[j][0], ez, fmaf(w[j][1], cz, w[j][2] * rz));
      float dx = fmaf(dw[j][0], ex, fmaf(dw[j][1], cx, dw[j][2] * rx));
      float dy = fmaf(dw[j][0], ey, fmaf(dw[j][1], cy, dw[j][2] * ry));
      float dz = fmaf(dw[j][0], ez, fmaf(dw[j][1], cz, dw[j][2] * rz));
      float dot = fmaf(px, dx, fmaf(py, dy, pz * dz));
      float dns = fmaf(dx, dx, fmaf(dy, dy, dz * dz));
      float f = (dot < 0.f) ? dot / (dns + 1e-6f) : 0.f;
      ax[j] += px - f * dx;
      ay[j] += py - f * dy;
      az[j] += pz - f * dz;
    }
  }
#pragma unroll
  for (int j = 0; j < 4; ++j) {
    int o = og * 4 + j;
    net0[((b * 64 + o) * 3 + 0) * N + n] = ax[j] * (1.f / 20.f);
    net0[((b * 64 + o) * 3 + 1) * N + n] = ay[j] * (1.f / 20.f);
    net0[((b * 64 + o) * 3 + 2) * N + n] = az[j] * (1.f / 20.f);
  }
}

// ---------------------------------------------------------------------------
// K4/K5/K6: VNT layer.  X[b][C][3][N] -> 128 out, VN-LeakyReLU.
// 1 point per thread, 4 outputs per thread, weights staged in LDS
// interleaved [c][j][w|d].  2048 blocks -> 8 blocks/CU, 32 waves/CU
// (launch_bounds(256,8) pins VGPR<=64 for full occupancy).
// HASPOOL: pooled-concat half computed in the prologue from poolsum.
// bid = og*64 + b*8 + nt: bid%8 = nt, so each XCD holds a 3.1MB X slice
// (all b, fixed nt) reused by all 32 og-groups.
// ---------------------------------------------------------------------------
template <int C, bool HASPOOL>
__global__ __launch_bounds__(256, 8) void vnt_layer_kernel(
    const float* __restrict__ X, const float* __restrict__ Wn,
    const float* __restrict__ Dm, int ldw,
    const float* __restrict__ poolin,
    float* __restrict__ Y, float* __restrict__ poolsum,
    float* __restrict__ outAcc) {
  __shared__ float wlds[C * 8];
  __shared__ float partp[12][16], partd[12][16];
  __shared__ float spadd[12], sdadd[12];
  int tid = threadIdx.x;
  int bid = blockIdx.x;
  int og = bid >> 6;
  int tile = bid & 63;
  int b = tile >> 3, nt = tile & 7;
  int o0 = og * 4;

  for (int i = tid; i < C * 8; i += 256) {
    int c = i >> 3, sl = i & 7, j = sl >> 1;
    const float* src = (sl & 1) ? Dm : Wn;
    wlds[i] = src[(o0 + j) * ldw + c];
  }
  if (HASPOOL) {
    if (tid < 192) {
      int jv = tid >> 4, ch = tid & 15;
      int j = jv / 3, v = jv % 3;
      float sp = 0.f, sd = 0.f;
#pragma unroll
      for (int cc = 0; cc < 8; ++cc) {
        int c = ch * 8 + cc;
        float x = poolin[(b * H + c) * 3 + v];
        sp = fmaf(Wn[(o0 + j) * ldw + C + c], x, sp);
        sd = fmaf(Dm[(o0 + j) * ldw + C + c], x, sd);
      }
      partp[jv][ch] = sp;
      partd[jv][ch] = sd;
    }
    __syncthreads();
    if (tid < 24) {
      int jv = tid % 12;
      bool isd = tid >= 12;
      float s = 0.f;
#pragma unroll
      for (int ch = 0; ch < 16; ++ch) s += (isd ? partd : partp)[jv][ch];
      (isd ? sdadd : spadd)[jv] = s * (1.f / 2048.f);
    }
  }
  __syncthreads();

  int n0 = nt * 256 + tid;

  float ap[4][3], ad[4][3];
#pragma unroll
  for (int j = 0; j < 4; ++j)
#pragma unroll
    for (int v = 0; v < 3; ++v) {
      ap[j][v] = HASPOOL ? spadd[j * 3 + v] : 0.f;
      ad[j][v] = HASPOOL ? sdadd[j * 3 + v] : 0.f;
    }

  const float* Xb = X + (size_t)b * C * 3 * N + n0;
#pragma unroll 2
  for (int c = 0; c < C; ++c) {
    float x0 = Xb[(c * 3 + 0) * N];
    float x1 = Xb[(c * 3 + 1) * N];
    float x2 = Xb[(c * 3 + 2) * N];
    float4 wd0 = *(const float4*)(wlds + c * 8);
    float4 wd1 = *(const float4*)(wlds + c * 8 + 4);
    float wj[4] = {wd0.x, wd0.z, wd1.x, wd1.z};
    float dj[4] = {wd0.y, wd0.w, wd1.y, wd1.w};
#pragma unroll
    for (int j = 0; j < 4; ++j) {
      ap[j][0] = fmaf(wj[j], x0, ap[j][0]);
      ap[j][1] = fmaf(wj[j], x1, ap[j][1]);
      ap[j][2] = fmaf(wj[j], x2, ap[j][2]);
      ad[j][0] = fmaf(dj[j], x0, ad[j][0]);
      ad[j][1] = fmaf(dj[j], x1, ad[j][1]);
      ad[j][2] = fmaf(dj[j], x2, ad[j][2]);
    }
  }

  // VN-LeakyReLU in place (ap becomes the result)
#pragma unroll
  for (int j = 0; j < 4; ++j) {
    float p0 = ap[j][0], p1 = ap[j][1], p2 = ap[j][2];
    float d0 = ad[j][0], d1 = ad[j][1], d2 = ad[j][2];
    float dot = fmaf(p0, d0, fmaf(p1, d1, p2 * d2));
    float dns = fmaf(d0, d0, fmaf(d1, d1, d2 * d2));
    float f = (dot < 0.f) ? dot / (dns + 1e-6f) : 0.f;
    ap[j][0] = p0 - f * d0;
    ap[j][1] = p1 - f * d1;
    ap[j][2] = p2 - f * d2;
  }

  if (Y) {
#pragma unroll
    for (int j = 0; j < 4; ++j)
#pragma unroll
      for (int v = 0; v < 3; ++v)
        Y[((size_t)(b * H + o0 + j) * 3 + v) * N + n0] = ap[j][v];
  }

  if (poolsum || outAcc) {
    __shared__ float red[12][4];
#pragma unroll
    for (int jv = 0; jv < 12; ++jv) {
      float r = ap[jv / 3][jv % 3];
#pragma unroll
      for (int off = 32; off > 0; off >>= 1) r += __shfl_down(r, off);
      if ((tid & 63) == 0) red[jv][tid >> 6] = r;
    }
    __syncthreads();
    if (tid < 12) {
      float t = red[tid][0] + red[tid][1] + red[tid][2] + red[tid][3];
      int j = tid / 3, v = tid % 3;
      if (poolsum)
        atomicAdd(poolsum + (b * H + o0 + j) * 3 + v, t);
      else
        atomicAdd(outAcc + b * 384 + (o0 + j) * 3 + v, t * (1.f / 2048.f));
    }
  }
}

// ---------------------------------------------------------------------------
// launch
// ---------------------------------------------------------------------------
extern "C" void kernel_launch(void* const* d_in, const int* in_sizes, int n_in,
                              void* d_out, int out_size, void* d_ws, size_t ws_size,
                              hipStream_t stream) {
  (void)in_sizes; (void)n_in; (void)out_size; (void)ws_size;
  const float* pc   = (const float*)d_in[0];
  const float* Wpos = (const float*)d_in[1];
  const float* Dpos = (const float*)d_in[2];
  const float* W1   = (const float*)d_in[3];
  const float* D1   = (const float*)d_in[4];
  const float* W2   = (const float*)d_in[5];
  const float* D2   = (const float*)d_in[6];
  const float* W3   = (const float*)d_in[7];
  const float* D3   = (const float*)d_in[8];
  float* out = (float*)d_out;
  float* ws  = (float*)d_ws;

  hipMemsetAsync(ws + OPS1, 0, 2 * 3072 * sizeof(float), stream);  // poolsum1+2
  hipMemsetAsync(out, 0, B * 384 * sizeof(float), stream);

  norm_rows_kernel<<<112, 256, 0, stream>>>(Wpos, W1, W2, W3, ws);
  knn_kernel<<<dim3(N / 4, B), 256, 0, stream>>>(pc, (int*)(ws + OIDX));
  edge_pos_kernel<<<dim3(16, 8, 8), 256, 0, stream>>>(
      pc, (const int*)(ws + OIDX), ws + OWNPOS, Dpos, ws + ONET0);
  // layer1: 64 -> 128, pool epilogue
  vnt_layer_kernel<64, false><<<2048, 256, 0, stream>>>(
      ws + ONET0, ws + OWN1, D1, 64, nullptr,
      ws + ONET1, ws + OPS1, nullptr);
  // layer2: 128(+pool prologue) -> 128, pool epilogue; net2 reuses net0 region
  vnt_layer_kernel<128, true><<<2048, 256, 0, stream>>>(
      ws + ONET1, ws + OWN2, D2, 256, ws + OPS1,
      ws + ONET0, ws + OPS2, nullptr);
  // layer3: 128(+pool prologue) -> 128, mean over N atomically into d_out
  vnt_layer_kernel<128, true><<<2048, 256, 0, stream>>>(
      ws + ONET0, ws + OWN3, D3, 256, ws + OPS2,
      nullptr, nullptr, out);
}